// Round 1
// baseline (533.157 us; speedup 1.0000x reference)
//
#include <hip/hip_runtime.h>

// MultiHeadAttention (mislabeled-einsum variant): per-position 16x16 head-mix.
// Pipeline: cvt weights -> 3x GEMM (QKV, bf16 MFMA) -> per-position attn -> GEMM (out).

typedef unsigned int u32;
typedef unsigned short u16;
typedef __attribute__((ext_vector_type(4))) float f32x4;
typedef __attribute__((ext_vector_type(8))) short bf16x8;

__device__ __forceinline__ void async_copy16(const void* g, void* l) {
  __builtin_amdgcn_global_load_lds(
      (const __attribute__((address_space(1))) void*)g,
      (__attribute__((address_space(3))) void*)l, 16, 0, 0);
}

// round-half-up fp32->bf16, packed pair into one u32 (lo = a, hi = b)
__device__ __forceinline__ u32 pk_bf16(float a, float b) {
  u32 ua = (__builtin_bit_cast(u32, a) + 0x8000u) >> 16;
  u32 ub = (__builtin_bit_cast(u32, b) + 0x8000u) & 0xFFFF0000u;
  return ua | ub;
}
__device__ __forceinline__ float bflo(u32 u) { return __builtin_bit_cast(float, u << 16); }
__device__ __forceinline__ float bfhi(u32 u) { return __builtin_bit_cast(float, u & 0xFFFF0000u); }

struct F8 { float f[8]; };
__device__ __forceinline__ F8 unp8(uint4 u) {
  F8 r;
  r.f[0] = bflo(u.x); r.f[1] = bfhi(u.x);
  r.f[2] = bflo(u.y); r.f[3] = bfhi(u.y);
  r.f[4] = bflo(u.z); r.f[5] = bfhi(u.z);
  r.f[6] = bflo(u.w); r.f[7] = bfhi(u.w);
  return r;
}

// ---- weight conversion: 4 matrices of 1024x1024 fp32 -> bf16 -------------
__global__ void cvt_w4(const float* __restrict__ s0, const float* __restrict__ s1,
                       const float* __restrict__ s2, const float* __restrict__ s3,
                       u16* __restrict__ dst) {
  int z = blockIdx.y;
  const float* s = (z == 0) ? s0 : (z == 1) ? s1 : (z == 2) ? s2 : s3;
  u16* d = dst + (size_t)z * (1024 * 1024);
  int i = (blockIdx.x * 256 + threadIdx.x) * 4;
  float4 f = *(const float4*)(s + i);
  uint2 u;
  u.x = pk_bf16(f.x, f.y);
  u.y = pk_bf16(f.z, f.w);
  *(uint2*)(d + i) = u;
}

// ---- GEMM: C[M,N] = A[M,1024] @ B[N,1024]^T + bias ------------------------
// 128x128 tile, BK=32, 256 threads (4 waves, 2x2), 4x4 mfma_f32_16x16x32_bf16/wave.
// AF32: A is fp32, converted to bf16 during staging. OUTBF: C written as bf16.
template <bool AF32, bool OUTBF>
__global__ void gemm_bt(const void* __restrict__ Ap, const u16* __restrict__ Bp,
                        const float* __restrict__ bias, void* __restrict__ Cp) {
  constexpr int KD = 1024;
  constexpr int ND = 1024;
  __shared__ alignas(16) u16 As[128 * 32];
  __shared__ alignas(16) u16 Bs[128 * 32];
  const int t = threadIdx.x;
  const int m0 = blockIdx.y * 128, n0 = blockIdx.x * 128;
  const int lane = t & 63, w = t >> 6;
  const int wr = (w >> 1) * 64, wc = (w & 1) * 64;
  const int lr = lane & 15, quad = lane >> 4;
  f32x4 acc[4][4] = {};

  for (int k0 = 0; k0 < KD; k0 += 32) {
    __syncthreads();
    // stage B tile (bf16) via async global->LDS, 16B per lane
#pragma unroll
    for (int i = 0; i < 2; i++) {
      int c = i * 256 + t;
      int r = c >> 2, c8 = (c & 3) * 8;
      async_copy16(Bp + ((size_t)(n0 + r) * KD + k0 + c8), &Bs[c * 8]);
    }
    if constexpr (AF32) {
      // stage A tile: fp32 loads, pack to bf16, ds_write
      const float* Af = (const float*)Ap;
      const int r = t >> 1, h = (t & 1) * 16;
      const float4* src = (const float4*)(Af + (size_t)(m0 + r) * KD + k0 + h);
      float4 f0 = src[0], f1 = src[1], f2 = src[2], f3 = src[3];
      uint4 u0 = { pk_bf16(f0.x, f0.y), pk_bf16(f0.z, f0.w),
                   pk_bf16(f1.x, f1.y), pk_bf16(f1.z, f1.w) };
      uint4 u1 = { pk_bf16(f2.x, f2.y), pk_bf16(f2.z, f2.w),
                   pk_bf16(f3.x, f3.y), pk_bf16(f3.z, f3.w) };
      uint4* dst = (uint4*)&As[r * 32 + h];
      dst[0] = u0;
      dst[1] = u1;
    } else {
      const u16* Ab = (const u16*)Ap;
#pragma unroll
      for (int i = 0; i < 2; i++) {
        int c = i * 256 + t;
        int r = c >> 2, c8 = (c & 3) * 8;
        async_copy16(Ab + ((size_t)(m0 + r) * KD + k0 + c8), &As[c * 8]);
      }
    }
    __syncthreads();

    bf16x8 af[4], bfr[4];
#pragma unroll
    for (int mi = 0; mi < 4; mi++)
      af[mi] = *(const bf16x8*)&As[(wr + mi * 16 + lr) * 32 + quad * 8];
#pragma unroll
    for (int ni = 0; ni < 4; ni++)
      bfr[ni] = *(const bf16x8*)&Bs[(wc + ni * 16 + lr) * 32 + quad * 8];
#pragma unroll
    for (int mi = 0; mi < 4; mi++)
#pragma unroll
      for (int ni = 0; ni < 4; ni++)
        acc[mi][ni] = __builtin_amdgcn_mfma_f32_16x16x32_bf16(af[mi], bfr[ni], acc[mi][ni], 0, 0, 0);
  }

  // epilogue: C row = m0+wr+mi*16+quad*4+r, col = n0+wc+ni*16+lr
#pragma unroll
  for (int ni = 0; ni < 4; ni++) {
    int col = n0 + wc + ni * 16 + lr;
    float bv = bias[col];
#pragma unroll
    for (int mi = 0; mi < 4; mi++) {
      int row = m0 + wr + mi * 16 + quad * 4;
#pragma unroll
      for (int r = 0; r < 4; r++) {
        float val = acc[mi][ni][r] + bv;
        if constexpr (OUTBF) {
          ((u16*)Cp)[(size_t)(row + r) * ND + col] =
              (u16)((__builtin_bit_cast(u32, val) + 0x8000u) >> 16);
        } else {
          ((float*)Cp)[(size_t)(row + r) * ND + col] = val;
        }
      }
    }
  }
}

// ---- per-position head-mix attention --------------------------------------
// one wave per (b,s) position. E[qh,kh] = Q_row[qh].K_row[kh]; softmax over kh
// (mask==0 -> uniform via zeroed scale); x[qh,:] = A[qh,:] @ V_rows.
__global__ void attn_mix(const u16* __restrict__ Q, const u16* __restrict__ K,
                         const u16* __restrict__ V, const int* __restrict__ mask,
                         u16* __restrict__ X) {
  __shared__ alignas(16) u16 qs[1024];
  __shared__ alignas(16) u16 ks[1024];
  __shared__ alignas(16) u16 vs[1024];
  __shared__ alignas(16) float Am[256];

  const int p = blockIdx.x;      // b*4096 + s
  const int lane = threadIdx.x;  // 0..63
  const size_t base = (size_t)p * 1024;

  {
    const uint4* Qg = (const uint4*)(Q + base);
    const uint4* Kg = (const uint4*)(K + base);
    const uint4* Vg = (const uint4*)(V + base);
    uint4* ql = (uint4*)qs; uint4* kl = (uint4*)ks; uint4* vl = (uint4*)vs;
    ql[lane] = Qg[lane]; ql[64 + lane] = Qg[64 + lane];
    kl[lane] = Kg[lane]; kl[64 + lane] = Kg[64 + lane];
    vl[lane] = Vg[lane]; vl[64 + lane] = Vg[64 + lane];
  }
  const int mk = mask[p];
  __syncthreads();

  // energies: lane handles qh = lane>>2, kh in {4g..4g+3}, g = lane&3
  const int qh = lane >> 2, g = lane & 3;
  float e0 = 0.f, e1 = 0.f, e2 = 0.f, e3 = 0.f;
  {
    const uint4* qr = (const uint4*)&qs[qh * 64];
    const uint4* k0r = (const uint4*)&ks[(g * 4 + 0) * 64];
    const uint4* k1r = (const uint4*)&ks[(g * 4 + 1) * 64];
    const uint4* k2r = (const uint4*)&ks[(g * 4 + 2) * 64];
    const uint4* k3r = (const uint4*)&ks[(g * 4 + 3) * 64];
#pragma unroll
    for (int c = 0; c < 8; c++) {
      F8 qf = unp8(qr[c]);
      F8 ka = unp8(k0r[c]), kb = unp8(k1r[c]), kc = unp8(k2r[c]), kd = unp8(k3r[c]);
#pragma unroll
      for (int j = 0; j < 8; j++) {
        e0 += qf.f[j] * ka.f[j];
        e1 += qf.f[j] * kb.f[j];
        e2 += qf.f[j] * kc.f[j];
        e3 += qf.f[j] * kd.f[j];
      }
    }
  }
  // softmax over kh (16 values spread over 4 lanes x 4 regs).
  // mask==0: energies all equal (-1e20) -> uniform; implement via scale=0.
  const float sc = mk ? 0.03125f : 0.0f;  // 1/sqrt(1024)
  float v0 = e0 * sc, v1 = e1 * sc, v2 = e2 * sc, v3 = e3 * sc;
  float mx = fmaxf(fmaxf(v0, v1), fmaxf(v2, v3));
  mx = fmaxf(mx, __shfl_xor(mx, 1, 64));
  mx = fmaxf(mx, __shfl_xor(mx, 2, 64));
  float p0 = __expf(v0 - mx), p1 = __expf(v1 - mx), p2 = __expf(v2 - mx), p3 = __expf(v3 - mx);
  float s = p0 + p1 + p2 + p3;
  s += __shfl_xor(s, 1, 64);
  s += __shfl_xor(s, 2, 64);
  float inv = 1.0f / s;
  Am[qh * 16 + g * 4 + 0] = p0 * inv;
  Am[qh * 16 + g * 4 + 1] = p1 * inv;
  Am[qh * 16 + g * 4 + 2] = p2 * inv;
  Am[qh * 16 + g * 4 + 3] = p3 * inv;
  __syncthreads();

  // x[qh2][c4*16 .. +15] = sum_kh A[qh2][kh] * V[kh][d]
  const int c4 = lane & 3, qh2 = lane >> 2;
  float xa[16];
#pragma unroll
  for (int i = 0; i < 16; i++) xa[i] = 0.f;
  const float* Ar = &Am[qh2 * 16];
#pragma unroll
  for (int kh = 0; kh < 16; kh++) {
    float wgt = Ar[kh];
    F8 va = unp8(*(const uint4*)&vs[kh * 64 + c4 * 16]);
    F8 vb = unp8(*(const uint4*)&vs[kh * 64 + c4 * 16 + 8]);
#pragma unroll
    for (int j = 0; j < 8; j++) {
      xa[j] += wgt * va.f[j];
      xa[8 + j] += wgt * vb.f[j];
    }
  }
  uint4 o0 = { pk_bf16(xa[0], xa[1]), pk_bf16(xa[2], xa[3]),
               pk_bf16(xa[4], xa[5]), pk_bf16(xa[6], xa[7]) };
  uint4 o1 = { pk_bf16(xa[8], xa[9]), pk_bf16(xa[10], xa[11]),
               pk_bf16(xa[12], xa[13]), pk_bf16(xa[14], xa[15]) };
  uint4* Xp = (uint4*)(X + base);
  Xp[lane * 2] = o0;
  Xp[lane * 2 + 1] = o1;
}

extern "C" void kernel_launch(void* const* d_in, const int* in_sizes, int n_in,
                              void* d_out, int out_size, void* d_ws, size_t ws_size,
                              hipStream_t stream) {
  const float* q    = (const float*)d_in[0];
  const float* k    = (const float*)d_in[1];
  const float* v    = (const float*)d_in[2];
  const int*   mask = (const int*)d_in[3];
  const float* Wq   = (const float*)d_in[4];
  const float* bq   = (const float*)d_in[5];
  const float* Wk   = (const float*)d_in[6];
  const float* bk   = (const float*)d_in[7];
  const float* Wv   = (const float*)d_in[8];
  const float* bv   = (const float*)d_in[9];
  const float* Wo   = (const float*)d_in[10];
  const float* bo   = (const float*)d_in[11];

  // ws layout (bf16 elems): 4 weights (1M each) + Q,K,V,X (16.78M each) = 142.6 MB
  u16* wsb = (u16*)d_ws;
  u16* Wqb = wsb;
  u16* Wkb = wsb + 1048576;
  u16* Wvb = wsb + 2097152;
  u16* Wob = wsb + 3145728;
  u16* Qb  = wsb + 4194304;
  u16* Kb  = Qb + 16777216;
  u16* Vb  = Kb + 16777216;
  u16* Xb  = Vb + 16777216;

  // 1) weights -> bf16
  cvt_w4<<<dim3(1024, 4), 256, 0, stream>>>(Wq, Wk, Wv, Wo, wsb);
  // 2) QKV projections: [16384,1024] = inp @ W^T + b  (out bf16)
  dim3 gg(8, 128);  // N/128, M/128
  gemm_bt<true, true><<<gg, 256, 0, stream>>>(q, Wqb, bq, Qb);
  gemm_bt<true, true><<<gg, 256, 0, stream>>>(k, Wkb, bk, Kb);
  gemm_bt<true, true><<<gg, 256, 0, stream>>>(v, Wvb, bv, Vb);
  // 3) per-position 16x16 head mix
  attn_mix<<<16384, 64, 0, stream>>>(Qb, Kb, Vb, mask, Xb);
  // 4) output projection (out fp32 -> d_out)
  gemm_bt<false, false><<<gg, 256, 0, stream>>>(Xb, Wob, bo, (float*)d_out);
}

// Round 2
// 483.378 us; speedup vs baseline: 1.1030x; 1.1030x over previous
//
#include <hip/hip_runtime.h>

// MultiHeadAttention (mislabeled-einsum variant): per-position 16x16 head-mix.
// Pipeline: cvt weights -> fused QKV GEMM (bf16 MFMA) -> per-position attn -> out GEMM.
// R2: fused QKV dispatch (3x occupancy), XCD-friendly block swizzle (blockIdx.x = m-strip
// so all n-blocks of a strip share an XCD L2 -> A fetched once), conflict-free A staging,
// barrier-free 4-wave attn kernel.

typedef unsigned int u32;
typedef unsigned short u16;
typedef __attribute__((ext_vector_type(4))) float f32x4;
typedef __attribute__((ext_vector_type(8))) short bf16x8;

__device__ __forceinline__ void async_copy16(const void* g, void* l) {
  __builtin_amdgcn_global_load_lds(
      (const __attribute__((address_space(1))) void*)g,
      (__attribute__((address_space(3))) void*)l, 16, 0, 0);
}

// round-half-up fp32->bf16, packed pair into one u32 (lo = a, hi = b)
__device__ __forceinline__ u32 pk_bf16(float a, float b) {
  u32 ua = (__builtin_bit_cast(u32, a) + 0x8000u) >> 16;
  u32 ub = (__builtin_bit_cast(u32, b) + 0x8000u) & 0xFFFF0000u;
  return ua | ub;
}
__device__ __forceinline__ float bflo(u32 u) { return __builtin_bit_cast(float, u << 16); }
__device__ __forceinline__ float bfhi(u32 u) { return __builtin_bit_cast(float, u & 0xFFFF0000u); }

struct F8 { float f[8]; };
__device__ __forceinline__ F8 unp8(uint4 u) {
  F8 r;
  r.f[0] = bflo(u.x); r.f[1] = bfhi(u.x);
  r.f[2] = bflo(u.y); r.f[3] = bfhi(u.y);
  r.f[4] = bflo(u.z); r.f[5] = bfhi(u.z);
  r.f[6] = bflo(u.w); r.f[7] = bfhi(u.w);
  return r;
}

// ---- weight conversion: 4 matrices of 1024x1024 fp32 -> bf16 -------------
__global__ void cvt_w4(const float* __restrict__ s0, const float* __restrict__ s1,
                       const float* __restrict__ s2, const float* __restrict__ s3,
                       u16* __restrict__ dst) {
  int z = blockIdx.y;
  const float* s = (z == 0) ? s0 : (z == 1) ? s1 : (z == 2) ? s2 : s3;
  u16* d = dst + (size_t)z * (1024 * 1024);
  int i = (blockIdx.x * 256 + threadIdx.x) * 4;
  float4 f = *(const float4*)(s + i);
  uint2 u;
  u.x = pk_bf16(f.x, f.y);
  u.y = pk_bf16(f.z, f.w);
  *(uint2*)(d + i) = u;
}

// ---- GEMM tile: C[m0:+128, n0:+128] = A[.,1024] @ B[.,1024]^T + bias ------
// 128x128 tile, BK=32, 256 threads (4 waves, 2x2), 4x4 mfma_f32_16x16x32_bf16/wave.
template <bool AF32, bool OUTBF>
__device__ __forceinline__ void gemm_tile(const void* __restrict__ Ap,
                                          const u16* __restrict__ Bp,
                                          const float* __restrict__ bias,
                                          void* __restrict__ Cp,
                                          int m0, int n0, u16* As, u16* Bs) {
  constexpr int KD = 1024;
  constexpr int ND = 1024;
  const int t = threadIdx.x;
  const int lane = t & 63, w = t >> 6;
  const int wr = (w >> 1) * 64, wc = (w & 1) * 64;
  const int lr = lane & 15, quad = lane >> 4;
  f32x4 acc[4][4] = {};

  for (int k0 = 0; k0 < KD; k0 += 32) {
    __syncthreads();
    // stage B tile (bf16) via async global->LDS, 16B per lane
#pragma unroll
    for (int i = 0; i < 2; i++) {
      int c = i * 256 + t;
      int r = c >> 2, c8 = (c & 3) * 8;
      async_copy16(Bp + ((size_t)(n0 + r) * KD + k0 + c8), &Bs[c * 8]);
    }
    if constexpr (AF32) {
      // stage A tile: fp32 loads, pack to bf16, lane-contiguous 16B ds_writes
      const float* Af = (const float*)Ap;
      const int r = t >> 2, c8 = (t & 3) * 8;
      const float4* s0 = (const float4*)(Af + (size_t)(m0 + r) * KD + k0 + c8);
      const float4* s1 = (const float4*)(Af + (size_t)(m0 + 64 + r) * KD + k0 + c8);
      float4 f0 = s0[0], f1 = s0[1];
      float4 f2 = s1[0], f3 = s1[1];
      uint4 u0 = { pk_bf16(f0.x, f0.y), pk_bf16(f0.z, f0.w),
                   pk_bf16(f1.x, f1.y), pk_bf16(f1.z, f1.w) };
      uint4 u1 = { pk_bf16(f2.x, f2.y), pk_bf16(f2.z, f2.w),
                   pk_bf16(f3.x, f3.y), pk_bf16(f3.z, f3.w) };
      *(uint4*)&As[t * 8] = u0;          // byte addr = t*16: conflict-free
      *(uint4*)&As[(256 + t) * 8] = u1;
    } else {
      const u16* Ab = (const u16*)Ap;
#pragma unroll
      for (int i = 0; i < 2; i++) {
        int c = i * 256 + t;
        int r = c >> 2, c8 = (c & 3) * 8;
        async_copy16(Ab + ((size_t)(m0 + r) * KD + k0 + c8), &As[c * 8]);
      }
    }
    __syncthreads();

    bf16x8 af[4], bfr[4];
#pragma unroll
    for (int mi = 0; mi < 4; mi++)
      af[mi] = *(const bf16x8*)&As[(wr + mi * 16 + lr) * 32 + quad * 8];
#pragma unroll
    for (int ni = 0; ni < 4; ni++)
      bfr[ni] = *(const bf16x8*)&Bs[(wc + ni * 16 + lr) * 32 + quad * 8];
#pragma unroll
    for (int mi = 0; mi < 4; mi++)
#pragma unroll
      for (int ni = 0; ni < 4; ni++)
        acc[mi][ni] = __builtin_amdgcn_mfma_f32_16x16x32_bf16(af[mi], bfr[ni], acc[mi][ni], 0, 0, 0);
  }

  // epilogue: C row = m0+wr+mi*16+quad*4+r, col = n0+wc+ni*16+lr
#pragma unroll
  for (int ni = 0; ni < 4; ni++) {
    int col = n0 + wc + ni * 16 + lr;
    float bv = bias[col];
#pragma unroll
    for (int mi = 0; mi < 4; mi++) {
      int row = m0 + wr + mi * 16 + quad * 4;
#pragma unroll
      for (int r = 0; r < 4; r++) {
        float val = acc[mi][ni][r] + bv;
        if constexpr (OUTBF) {
          ((u16*)Cp)[(size_t)(row + r) * ND + col] =
              (u16)((__builtin_bit_cast(u32, val) + 0x8000u) >> 16);
        } else {
          ((float*)Cp)[(size_t)(row + r) * ND + col] = val;
        }
      }
    }
  }
}

// fused QKV projection: grid (M/128, N/128, 3); blockIdx.x = m-strip (fastest)
// so the 8 n-blocks of a strip map to the same XCD (linear%8 == x%8).
__global__ __launch_bounds__(256) void gemm_qkv(
    const float* __restrict__ q, const float* __restrict__ k, const float* __restrict__ v,
    const u16* __restrict__ W, const float* __restrict__ bq, const float* __restrict__ bk,
    const float* __restrict__ bv, u16* __restrict__ out) {
  __shared__ alignas(16) u16 As[128 * 32];
  __shared__ alignas(16) u16 Bs[128 * 32];
  const int z = blockIdx.z;
  const float* A = (z == 0) ? q : (z == 1) ? k : v;
  const float* bias = (z == 0) ? bq : (z == 1) ? bk : bv;
  gemm_tile<true, true>(A, W + (size_t)z * 1048576, bias, out + (size_t)z * 16777216,
                        blockIdx.x * 128, blockIdx.y * 128, As, Bs);
}

__global__ __launch_bounds__(256) void gemm_o(
    const u16* __restrict__ X, const u16* __restrict__ W,
    const float* __restrict__ bias, float* __restrict__ C) {
  __shared__ alignas(16) u16 As[128 * 32];
  __shared__ alignas(16) u16 Bs[128 * 32];
  gemm_tile<false, false>(X, W, bias, C, blockIdx.x * 128, blockIdx.y * 128, As, Bs);
}

// ---- per-position head-mix attention --------------------------------------
// 4 waves/block, one position per wave, no barriers (per-wave LDS regions).
// E[qh,kh] = Q_row[qh].K_row[kh]; softmax over kh (mask==0 -> uniform via
// zeroed scale); x[qh,:] = A[qh,:] @ V_rows. Attention weights distributed
// via shuffles (4-lane groups), not LDS.
__global__ __launch_bounds__(256) void attn_mix(
    const u16* __restrict__ Q, const u16* __restrict__ K,
    const u16* __restrict__ V, const int* __restrict__ mask,
    u16* __restrict__ X) {
  __shared__ alignas(16) u16 qs[4][1024];
  __shared__ alignas(16) u16 ks[4][1024];
  __shared__ alignas(16) u16 vs[4][1024];

  const int w = threadIdx.x >> 6;
  const int lane = threadIdx.x & 63;
  const int p = blockIdx.x * 4 + w;  // b*4096 + s
  const size_t base = (size_t)p * 1024;

  {
    const uint4* Qg = (const uint4*)(Q + base);
    const uint4* Kg = (const uint4*)(K + base);
    const uint4* Vg = (const uint4*)(V + base);
    uint4* ql = (uint4*)qs[w]; uint4* kl = (uint4*)ks[w]; uint4* vl = (uint4*)vs[w];
    ql[lane] = Qg[lane]; ql[64 + lane] = Qg[64 + lane];
    kl[lane] = Kg[lane]; kl[64 + lane] = Kg[64 + lane];
    vl[lane] = Vg[lane]; vl[64 + lane] = Vg[64 + lane];
  }
  const int mk = mask[p];
  // no __syncthreads: same-wave LDS RAW handled by lgkmcnt

  // energies: lane (qh = lane>>2, g = lane&3) handles kh in {4g..4g+3}
  const int qh = lane >> 2, g = lane & 3;
  float e0 = 0.f, e1 = 0.f, e2 = 0.f, e3 = 0.f;
  {
    const uint4* qr = (const uint4*)&qs[w][qh * 64];
    const uint4* k0r = (const uint4*)&ks[w][(g * 4 + 0) * 64];
    const uint4* k1r = (const uint4*)&ks[w][(g * 4 + 1) * 64];
    const uint4* k2r = (const uint4*)&ks[w][(g * 4 + 2) * 64];
    const uint4* k3r = (const uint4*)&ks[w][(g * 4 + 3) * 64];
#pragma unroll
    for (int c = 0; c < 8; c++) {
      F8 qf = unp8(qr[c]);
      F8 ka = unp8(k0r[c]), kb = unp8(k1r[c]), kc = unp8(k2r[c]), kd = unp8(k3r[c]);
#pragma unroll
      for (int j = 0; j < 8; j++) {
        e0 += qf.f[j] * ka.f[j];
        e1 += qf.f[j] * kb.f[j];
        e2 += qf.f[j] * kc.f[j];
        e3 += qf.f[j] * kd.f[j];
      }
    }
  }
  // softmax over kh (16 values spread over 4 lanes x 4 regs).
  const float sc = mk ? 0.03125f : 0.0f;  // 1/sqrt(1024); mask==0 -> uniform
  float v0 = e0 * sc, v1 = e1 * sc, v2 = e2 * sc, v3 = e3 * sc;
  float mx = fmaxf(fmaxf(v0, v1), fmaxf(v2, v3));
  mx = fmaxf(mx, __shfl_xor(mx, 1, 64));
  mx = fmaxf(mx, __shfl_xor(mx, 2, 64));
  float p0 = __expf(v0 - mx), p1 = __expf(v1 - mx), p2 = __expf(v2 - mx), p3 = __expf(v3 - mx);
  float s = p0 + p1 + p2 + p3;
  s += __shfl_xor(s, 1, 64);
  s += __shfl_xor(s, 2, 64);
  float inv = 1.0f / s;
  float a0 = p0 * inv, a1 = p1 * inv, a2 = p2 * inv, a3 = p3 * inv;

  // x[qh][c4*16 .. +15] = sum_kh A[qh][kh] * V[kh][..]; weights via shuffle
  const int c4 = g;  // reuse lane decomposition
  float xa[16];
#pragma unroll
  for (int i = 0; i < 16; i++) xa[i] = 0.f;
#pragma unroll
  for (int g2 = 0; g2 < 4; g2++) {
    int src = (lane & ~3) | g2;  // lane (qh, g2)
    float w0 = __shfl(a0, src, 64);
    float w1 = __shfl(a1, src, 64);
    float w2 = __shfl(a2, src, 64);
    float w3 = __shfl(a3, src, 64);
    const float wv[4] = { w0, w1, w2, w3 };
#pragma unroll
    for (int j4 = 0; j4 < 4; j4++) {
      int kh = g2 * 4 + j4;
      float wgt = wv[j4];
      F8 va = unp8(*(const uint4*)&vs[w][kh * 64 + c4 * 16]);
      F8 vb = unp8(*(const uint4*)&vs[w][kh * 64 + c4 * 16 + 8]);
#pragma unroll
      for (int j = 0; j < 8; j++) {
        xa[j] += wgt * va.f[j];
        xa[8 + j] += wgt * vb.f[j];
      }
    }
  }
  uint4 o0 = { pk_bf16(xa[0], xa[1]), pk_bf16(xa[2], xa[3]),
               pk_bf16(xa[4], xa[5]), pk_bf16(xa[6], xa[7]) };
  uint4 o1 = { pk_bf16(xa[8], xa[9]), pk_bf16(xa[10], xa[11]),
               pk_bf16(xa[12], xa[13]), pk_bf16(xa[14], xa[15]) };
  uint4* Xp = (uint4*)(X + base);
  Xp[lane * 2] = o0;       // chunk qh*8 + c4*2 == lane*2
  Xp[lane * 2 + 1] = o1;
}

extern "C" void kernel_launch(void* const* d_in, const int* in_sizes, int n_in,
                              void* d_out, int out_size, void* d_ws, size_t ws_size,
                              hipStream_t stream) {
  const float* q    = (const float*)d_in[0];
  const float* k    = (const float*)d_in[1];
  const float* v    = (const float*)d_in[2];
  const int*   mask = (const int*)d_in[3];
  const float* Wq   = (const float*)d_in[4];
  const float* bq   = (const float*)d_in[5];
  const float* Wk   = (const float*)d_in[6];
  const float* bk   = (const float*)d_in[7];
  const float* Wv   = (const float*)d_in[8];
  const float* bv   = (const float*)d_in[9];
  const float* Wo   = (const float*)d_in[10];
  const float* bo   = (const float*)d_in[11];

  // ws layout (bf16 elems): 4 weights (1M each) + Q,K,V,X (16.78M each) = 142.6 MB
  u16* wsb = (u16*)d_ws;
  u16* Wqkv = wsb;                    // Wq,Wk,Wv consecutive
  u16* Wob  = wsb + 3145728;
  u16* Qb   = wsb + 4194304;          // Q,K,V consecutive
  u16* Kb   = Qb + 16777216;
  u16* Vb   = Kb + 16777216;
  u16* Xb   = Vb + 16777216;

  // 1) weights -> bf16
  cvt_w4<<<dim3(1024, 4), 256, 0, stream>>>(Wq, Wk, Wv, Wo, wsb);
  // 2) fused QKV projections: [16384,1024] = inp @ W^T + b (out bf16)
  gemm_qkv<<<dim3(128, 8, 3), 256, 0, stream>>>(q, k, v, Wqkv, bq, bk, bv, Qb);
  // 3) per-position 16x16 head mix
  attn_mix<<<4096, 256, 0, stream>>>(Qb, Kb, Vb, mask, Xb);
  // 4) output projection (out fp32 -> d_out)
  gemm_o<<<dim3(128, 8), 256, 0, stream>>>(Xb, Wob, bo, (float*)d_out);
}

// Round 3
// 462.310 us; speedup vs baseline: 1.1532x; 1.0456x over previous
//
#include <hip/hip_runtime.h>

// MultiHeadAttention (mislabeled-einsum variant): per-position 16x16 head-mix.
// R3: pre-convert inputs to bf16 (pure global_load_lds GEMMs), per-XCD m-strip
// swizzle (n fastest within strip -> A-strip + W fit in 4MB XCD L2), padded attn
// LDS (72-elem row stride kills the 16-way Q-row bank conflict).

typedef unsigned int u32;
typedef unsigned short u16;
typedef __attribute__((ext_vector_type(4))) float f32x4;
typedef __attribute__((ext_vector_type(8))) short bf16x8;

__device__ __forceinline__ void async_copy16(const void* g, void* l) {
  __builtin_amdgcn_global_load_lds(
      (const __attribute__((address_space(1))) void*)g,
      (__attribute__((address_space(3))) void*)l, 16, 0, 0);
}

// round-half-up fp32->bf16, packed pair into one u32 (lo = a, hi = b)
__device__ __forceinline__ u32 pk_bf16(float a, float b) {
  u32 ua = (__builtin_bit_cast(u32, a) + 0x8000u) >> 16;
  u32 ub = (__builtin_bit_cast(u32, b) + 0x8000u) & 0xFFFF0000u;
  return ua | ub;
}
__device__ __forceinline__ float bflo(u32 u) { return __builtin_bit_cast(float, u << 16); }
__device__ __forceinline__ float bfhi(u32 u) { return __builtin_bit_cast(float, u & 0xFFFF0000u); }

struct F8 { float f[8]; };
__device__ __forceinline__ F8 unp8(uint4 u) {
  F8 r;
  r.f[0] = bflo(u.x); r.f[1] = bfhi(u.x);
  r.f[2] = bflo(u.y); r.f[3] = bfhi(u.y);
  r.f[4] = bflo(u.z); r.f[5] = bfhi(u.z);
  r.f[6] = bflo(u.w); r.f[7] = bfhi(u.w);
  return r;
}

// ---- weight conversion: 4 matrices of 1024x1024 fp32 -> bf16 -------------
__global__ void cvt_w4(const float* __restrict__ s0, const float* __restrict__ s1,
                       const float* __restrict__ s2, const float* __restrict__ s3,
                       u16* __restrict__ dst) {
  int z = blockIdx.y;
  const float* s = (z == 0) ? s0 : (z == 1) ? s1 : (z == 2) ? s2 : s3;
  u16* d = dst + (size_t)z * (1024 * 1024);
  int i = (blockIdx.x * 256 + threadIdx.x) * 4;
  float4 f = *(const float4*)(s + i);
  uint2 u;
  u.x = pk_bf16(f.x, f.y);
  u.y = pk_bf16(f.z, f.w);
  *(uint2*)(d + i) = u;
}

// ---- input conversion: q,k,v [16777216 fp32 each] -> bf16 -----------------
__global__ void cvt_in3(const float* __restrict__ s0, const float* __restrict__ s1,
                        const float* __restrict__ s2, u16* __restrict__ dst) {
  int z = blockIdx.y;
  const float* s = (z == 0) ? s0 : (z == 1) ? s1 : s2;
  u16* d = dst + (size_t)z * 16777216;
  int i = (blockIdx.x * 256 + threadIdx.x) * 4;
  float4 f = *(const float4*)(s + i);
  uint2 u;
  u.x = pk_bf16(f.x, f.y);
  u.y = pk_bf16(f.z, f.w);
  *(uint2*)(d + i) = u;
}

// ---- GEMM tile: C[m0:+128, n0:+128] = A[.,1024] @ B[.,1024]^T + bias ------
// 128x128 tile, BK=32, 256 threads (4 waves, 2x2), 4x4 mfma_f32_16x16x32_bf16/wave.
template <bool AF32, bool OUTBF>
__device__ __forceinline__ void gemm_tile(const void* __restrict__ Ap,
                                          const u16* __restrict__ Bp,
                                          const float* __restrict__ bias,
                                          void* __restrict__ Cp,
                                          int m0, int n0, u16* As, u16* Bs) {
  constexpr int KD = 1024;
  constexpr int ND = 1024;
  const int t = threadIdx.x;
  const int lane = t & 63, w = t >> 6;
  const int wr = (w >> 1) * 64, wc = (w & 1) * 64;
  const int lr = lane & 15, quad = lane >> 4;
  f32x4 acc[4][4] = {};

  for (int k0 = 0; k0 < KD; k0 += 32) {
    __syncthreads();
    // stage B tile (bf16) via async global->LDS, 16B per lane
#pragma unroll
    for (int i = 0; i < 2; i++) {
      int c = i * 256 + t;
      int r = c >> 2, c8 = (c & 3) * 8;
      async_copy16(Bp + ((size_t)(n0 + r) * KD + k0 + c8), &Bs[c * 8]);
    }
    if constexpr (AF32) {
      // fallback: stage A from fp32, pack to bf16, lane-contiguous 16B ds_writes
      const float* Af = (const float*)Ap;
      const int r = t >> 2, c8 = (t & 3) * 8;
      const float4* s0 = (const float4*)(Af + (size_t)(m0 + r) * KD + k0 + c8);
      const float4* s1 = (const float4*)(Af + (size_t)(m0 + 64 + r) * KD + k0 + c8);
      float4 f0 = s0[0], f1 = s0[1];
      float4 f2 = s1[0], f3 = s1[1];
      uint4 u0 = { pk_bf16(f0.x, f0.y), pk_bf16(f0.z, f0.w),
                   pk_bf16(f1.x, f1.y), pk_bf16(f1.z, f1.w) };
      uint4 u1 = { pk_bf16(f2.x, f2.y), pk_bf16(f2.z, f2.w),
                   pk_bf16(f3.x, f3.y), pk_bf16(f3.z, f3.w) };
      *(uint4*)&As[t * 8] = u0;
      *(uint4*)&As[(256 + t) * 8] = u1;
    } else {
      const u16* Ab = (const u16*)Ap;
#pragma unroll
      for (int i = 0; i < 2; i++) {
        int c = i * 256 + t;
        int r = c >> 2, c8 = (c & 3) * 8;
        async_copy16(Ab + ((size_t)(m0 + r) * KD + k0 + c8), &As[c * 8]);
      }
    }
    __syncthreads();

    bf16x8 af[4], bfr[4];
#pragma unroll
    for (int mi = 0; mi < 4; mi++)
      af[mi] = *(const bf16x8*)&As[(wr + mi * 16 + lr) * 32 + quad * 8];
#pragma unroll
    for (int ni = 0; ni < 4; ni++)
      bfr[ni] = *(const bf16x8*)&Bs[(wc + ni * 16 + lr) * 32 + quad * 8];
#pragma unroll
    for (int mi = 0; mi < 4; mi++)
#pragma unroll
      for (int ni = 0; ni < 4; ni++)
        acc[mi][ni] = __builtin_amdgcn_mfma_f32_16x16x32_bf16(af[mi], bfr[ni], acc[mi][ni], 0, 0, 0);
  }

  // epilogue: C row = m0+wr+mi*16+quad*4+r, col = n0+wc+ni*16+lr
#pragma unroll
  for (int ni = 0; ni < 4; ni++) {
    int col = n0 + wc + ni * 16 + lr;
    float bv = bias[col];
#pragma unroll
    for (int mi = 0; mi < 4; mi++) {
      int row = m0 + wr + mi * 16 + quad * 4;
#pragma unroll
      for (int r = 0; r < 4; r++) {
        float val = acc[mi][ni][r] + bv;
        if constexpr (OUTBF) {
          ((u16*)Cp)[(size_t)(row + r) * ND + col] =
              (u16)((__builtin_bit_cast(u32, val) + 0x8000u) >> 16);
        } else {
          ((float*)Cp)[(size_t)(row + r) * ND + col] = val;
        }
      }
    }
  }
}

// fused QKV projection. 1D grid of 3072 blocks; decode so XCD c (= lin%8) owns
// m-strips [16c,16c+16), iterating n fastest: per-XCD hot set = one 256KB A-strip
// + 2MB weight matrix, fits the 4MB XCD L2.
template <bool AF32>
__global__ __launch_bounds__(256) void gemm_qkv(
    const void* __restrict__ a0, const void* __restrict__ a1, const void* __restrict__ a2,
    const u16* __restrict__ W, const float* __restrict__ b0, const float* __restrict__ b1,
    const float* __restrict__ b2, u16* __restrict__ out) {
  __shared__ alignas(16) u16 As[128 * 32];
  __shared__ alignas(16) u16 Bs[128 * 32];
  const int lin = blockIdx.x;
  const int c = lin & 7;          // XCD
  const int i = lin >> 3;         // 0..383 per-XCD sequence
  const int z = i >> 7;           // tensor 0..2 (outermost: weights stay hot)
  const int r = i & 127;
  const int m = c * 16 + (r >> 3);
  const int n = r & 7;
  const void* A = (z == 0) ? a0 : (z == 1) ? a1 : a2;
  const float* bias = (z == 0) ? b0 : (z == 1) ? b1 : b2;
  gemm_tile<AF32, true>(A, W + (size_t)z * 1048576, bias, out + (size_t)z * 16777216,
                        m * 128, n * 128, As, Bs);
}

__global__ __launch_bounds__(256) void gemm_o(
    const u16* __restrict__ X, const u16* __restrict__ W,
    const float* __restrict__ bias, float* __restrict__ C) {
  __shared__ alignas(16) u16 As[128 * 32];
  __shared__ alignas(16) u16 Bs[128 * 32];
  const int lin = blockIdx.x;
  const int c = lin & 7;
  const int i = lin >> 3;         // 0..127
  const int m = c * 16 + (i >> 3);
  const int n = i & 7;
  gemm_tile<false, false>(X, W, bias, C, m * 128, n * 128, As, Bs);
}

// ---- per-position head-mix attention --------------------------------------
// 4 waves/block, one position per wave, no barriers. LDS rows padded to 72
// elems (144 B): Q-row reads that were 16-way bank-conflicted become 2-way (free).
__global__ __launch_bounds__(256) void attn_mix(
    const u16* __restrict__ Q, const u16* __restrict__ K,
    const u16* __restrict__ V, const int* __restrict__ mask,
    u16* __restrict__ X) {
  constexpr int RS = 72;  // padded row stride (elems); 144 B, 16B-aligned
  __shared__ alignas(16) u16 qs[4][16 * RS];
  __shared__ alignas(16) u16 ks[4][16 * RS];
  __shared__ alignas(16) u16 vs[4][16 * RS];

  const int w = threadIdx.x >> 6;
  const int lane = threadIdx.x & 63;
  const int p = blockIdx.x * 4 + w;  // b*4096 + s
  const size_t base = (size_t)p * 1024;

  {
    const uint4* Qg = (const uint4*)(Q + base);
    const uint4* Kg = (const uint4*)(K + base);
    const uint4* Vg = (const uint4*)(V + base);
#pragma unroll
    for (int h = 0; h < 2; h++) {
      int j = h * 64 + lane;              // chunk 0..127
      int off = (j >> 3) * RS + (j & 7) * 8;  // padded elem offset
      *(uint4*)&qs[w][off] = Qg[j];
      *(uint4*)&ks[w][off] = Kg[j];
      *(uint4*)&vs[w][off] = Vg[j];
    }
  }
  const int mk = mask[p];
  // same-wave LDS RAW: handled by lgkmcnt, no barrier needed

  // energies: lane (qh = lane>>2, g = lane&3) handles kh in {4g..4g+3}
  const int qh = lane >> 2, g = lane & 3;
  float e0 = 0.f, e1 = 0.f, e2 = 0.f, e3 = 0.f;
  {
    const u16* qr = &qs[w][qh * RS];
    const u16* k0r = &ks[w][(g * 4 + 0) * RS];
    const u16* k1r = &ks[w][(g * 4 + 1) * RS];
    const u16* k2r = &ks[w][(g * 4 + 2) * RS];
    const u16* k3r = &ks[w][(g * 4 + 3) * RS];
#pragma unroll
    for (int c = 0; c < 8; c++) {
      F8 qf = unp8(*(const uint4*)&qr[c * 8]);
      F8 ka = unp8(*(const uint4*)&k0r[c * 8]);
      F8 kb = unp8(*(const uint4*)&k1r[c * 8]);
      F8 kc = unp8(*(const uint4*)&k2r[c * 8]);
      F8 kd = unp8(*(const uint4*)&k3r[c * 8]);
#pragma unroll
      for (int j = 0; j < 8; j++) {
        e0 += qf.f[j] * ka.f[j];
        e1 += qf.f[j] * kb.f[j];
        e2 += qf.f[j] * kc.f[j];
        e3 += qf.f[j] * kd.f[j];
      }
    }
  }
  // softmax over kh (16 values spread over 4 lanes x 4 regs)
  const float sc = mk ? 0.03125f : 0.0f;  // 1/sqrt(1024); mask==0 -> uniform
  float v0 = e0 * sc, v1 = e1 * sc, v2 = e2 * sc, v3 = e3 * sc;
  float mx = fmaxf(fmaxf(v0, v1), fmaxf(v2, v3));
  mx = fmaxf(mx, __shfl_xor(mx, 1, 64));
  mx = fmaxf(mx, __shfl_xor(mx, 2, 64));
  float p0 = __expf(v0 - mx), p1 = __expf(v1 - mx), p2 = __expf(v2 - mx), p3 = __expf(v3 - mx);
  float s = p0 + p1 + p2 + p3;
  s += __shfl_xor(s, 1, 64);
  s += __shfl_xor(s, 2, 64);
  float inv = 1.0f / s;
  float a0 = p0 * inv, a1 = p1 * inv, a2 = p2 * inv, a3 = p3 * inv;

  // x[qh][g*16 .. +15] = sum_kh A[qh][kh] * V[kh][..]; weights via shuffle
  float xa[16];
#pragma unroll
  for (int i = 0; i < 16; i++) xa[i] = 0.f;
#pragma unroll
  for (int g2 = 0; g2 < 4; g2++) {
    int src = (lane & ~3) | g2;  // lane (qh, g2)
    float w0 = __shfl(a0, src, 64);
    float w1 = __shfl(a1, src, 64);
    float w2 = __shfl(a2, src, 64);
    float w3 = __shfl(a3, src, 64);
    const float wv[4] = { w0, w1, w2, w3 };
#pragma unroll
    for (int j4 = 0; j4 < 4; j4++) {
      int kh = g2 * 4 + j4;
      float wgt = wv[j4];
      F8 va = unp8(*(const uint4*)&vs[w][kh * RS + g * 16]);
      F8 vb = unp8(*(const uint4*)&vs[w][kh * RS + g * 16 + 8]);
#pragma unroll
      for (int j = 0; j < 8; j++) {
        xa[j] += wgt * va.f[j];
        xa[8 + j] += wgt * vb.f[j];
      }
    }
  }
  uint4 o0 = { pk_bf16(xa[0], xa[1]), pk_bf16(xa[2], xa[3]),
               pk_bf16(xa[4], xa[5]), pk_bf16(xa[6], xa[7]) };
  uint4 o1 = { pk_bf16(xa[8], xa[9]), pk_bf16(xa[10], xa[11]),
               pk_bf16(xa[12], xa[13]), pk_bf16(xa[14], xa[15]) };
  uint4* Xp = (uint4*)(X + base);
  Xp[lane * 2] = o0;       // chunk qh*8 + g*2 == lane*2
  Xp[lane * 2 + 1] = o1;
}

extern "C" void kernel_launch(void* const* d_in, const int* in_sizes, int n_in,
                              void* d_out, int out_size, void* d_ws, size_t ws_size,
                              hipStream_t stream) {
  const float* q    = (const float*)d_in[0];
  const float* k    = (const float*)d_in[1];
  const float* v    = (const float*)d_in[2];
  const int*   mask = (const int*)d_in[3];
  const float* Wq   = (const float*)d_in[4];
  const float* bq   = (const float*)d_in[5];
  const float* Wk   = (const float*)d_in[6];
  const float* bk   = (const float*)d_in[7];
  const float* Wv   = (const float*)d_in[8];
  const float* bv   = (const float*)d_in[9];
  const float* Wo   = (const float*)d_in[10];
  const float* bo   = (const float*)d_in[11];

  u16* wsb = (u16*)d_ws;
  const bool big = ws_size >= 209715200ull;  // 200 MiB path

  if (big) {
    // layout (u16 elems): Wqkv[3M] Wo[1M] qb/kb/vb[3x16.78M] Q/K/V[3x16.78M]; X aliases qb
    u16* Wqkv = wsb;
    u16* Wob  = wsb + 3145728;
    u16* qb   = wsb + 4194304;
    u16* Qb   = wsb + 54525952;
    u16* Kb   = Qb + 16777216;
    u16* Vb   = Kb + 16777216;
    u16* Xb   = qb;  // qb/kb/vb dead after gemm_qkv
    cvt_w4<<<dim3(1024, 4), 256, 0, stream>>>(Wq, Wk, Wv, Wo, wsb);
    cvt_in3<<<dim3(16384, 3), 256, 0, stream>>>(q, k, v, qb);
    gemm_qkv<false><<<3072, 256, 0, stream>>>(qb, qb + 16777216, qb + 33554432,
                                              Wqkv, bq, bk, bv, Qb);
    attn_mix<<<4096, 256, 0, stream>>>(Qb, Kb, Vb, mask, Xb);
    gemm_o<<<1024, 256, 0, stream>>>(Xb, Wob, bo, (float*)d_out);
  } else {
    // fallback: fp32-A in-staging path (142.6 MB)
    u16* Wqkv = wsb;
    u16* Wob  = wsb + 3145728;
    u16* Qb   = wsb + 4194304;
    u16* Kb   = Qb + 16777216;
    u16* Vb   = Kb + 16777216;
    u16* Xb   = Vb + 16777216;
    cvt_w4<<<dim3(1024, 4), 256, 0, stream>>>(Wq, Wk, Wv, Wo, wsb);
    gemm_qkv<true><<<3072, 256, 0, stream>>>(q, k, v, Wqkv, bq, bk, bv, Qb);
    attn_mix<<<4096, 256, 0, stream>>>(Qb, Kb, Vb, mask, Xb);
    gemm_o<<<1024, 256, 0, stream>>>(Xb, Wob, bo, (float*)d_out);
  }
}